// Round 4
// baseline (173.197 us; speedup 1.0000x reference)
//
#include <hip/hip_runtime.h>

// PreHTSK fused, MFMA edition v3 — 3 launches, barrier-free GEMM.
// out[b,o] = rstd*(S + T) - mu*rstd*G[o] + Bb[o]
//   S = sum_r frs[b,r] * sum_i X[b,i]*gamma[r*256+i]*W[o, r*256+i]   (MFMA, A=X in regs,
//       B-fragments read directly from global Bpack — pre-packed in lane order)
//   T = sum_r frs[b,r] * Wtail[r][o]                                  (epilogue)
// LN closed-form: mu=(Sx+1)/D, E[f^2]=Q*(Sx2+1)/D, Q=sum frs^2 (sum frs = 1).

#define B_    2048
#define IN_   256
#define NR_   128
#define OUT_  64
#define D_    32896
#define XP_   32768
#define KSPLIT 16   // rule-groups; 8 rules per gemm block

typedef short s16x8 __attribute__((ext_vector_type(8)));
typedef float f32x4 __attribute__((ext_vector_type(4)));

__device__ __forceinline__ unsigned short bfc(float f) {
  union { float f; unsigned int u; } v; v.f = f;
  unsigned int r = (v.u + 0x7fffu + ((v.u >> 16) & 1u)) >> 16;  // RNE
  return (unsigned short)r;
}

// ================= Kernel A: block-specialized prep-pack (0..127) + frs (128..383)
// pack: Bpack[rule][kc(8)][ct(4)][lane(64)][j(8)], elem (k=kc*32+(lane>>4)*8+j, o=ct*16+(lane&15))
//       + Gpart/Bpart[rule*8+kc][o] partial reductions of gamma*W / beta*W.
// frs:  8 rows/block: pre[b,r] = -(1/256) sum_i (x-c)^2 * s ; softmax; LN stats; X->bf16.
__global__ __launch_bounds__(512) void prep_frs_kernel(
    const float* __restrict__ X, const float* __restrict__ centers,
    const float* __restrict__ sigmas, const float* __restrict__ W,
    const float* __restrict__ gamma, const float* __restrict__ beta,
    unsigned short* __restrict__ Bpack, float* __restrict__ Gpart,
    float* __restrict__ Bpart, float* __restrict__ frs,
    float* __restrict__ rstdO, float* __restrict__ murO,
    unsigned short* __restrict__ Xbf) {
  __shared__ float Xs[8][256];
  __shared__ float pre[4][8][128];
  int tid = threadIdx.x;

  if (blockIdx.x < 128) {       // ---- pack path: wave per kc
    int r = blockIdx.x;
    int kc = tid >> 6, lane = tid & 63;
    int d0 = r * 256 + kc * 32 + (lane >> 4) * 8;
    float4 g0  = *(const float4*)&gamma[d0];
    float4 g1  = *(const float4*)&gamma[d0 + 4];
    float4 be0 = *(const float4*)&beta[d0];
    float4 be1 = *(const float4*)&beta[d0 + 4];
    int rb = r * 8 + kc;
#pragma unroll
    for (int ct = 0; ct < 4; ct++) {
      int o = ct * 16 + (lane & 15);
      const float* wp = &W[(size_t)o * D_ + d0];
      float4 w0 = *(const float4*)wp;
      float4 w1 = *(const float4*)(wp + 4);
      unsigned int u[4];
      u[0] = bfc(w0.x * g0.x) | ((unsigned int)bfc(w0.y * g0.y) << 16);
      u[1] = bfc(w0.z * g0.z) | ((unsigned int)bfc(w0.w * g0.w) << 16);
      u[2] = bfc(w1.x * g1.x) | ((unsigned int)bfc(w1.y * g1.y) << 16);
      u[3] = bfc(w1.z * g1.z) | ((unsigned int)bfc(w1.w * g1.w) << 16);
      *(uint4*)&Bpack[((size_t)(rb * 4 + ct) * 64 + lane) * 8] = make_uint4(u[0], u[1], u[2], u[3]);
      float gs = w0.x*g0.x + w0.y*g0.y + w0.z*g0.z + w0.w*g0.w
               + w1.x*g1.x + w1.y*g1.y + w1.z*g1.z + w1.w*g1.w;
      float bs = w0.x*be0.x + w0.y*be0.y + w0.z*be0.z + w0.w*be0.w
               + w1.x*be1.x + w1.y*be1.y + w1.z*be1.z + w1.w*be1.w;
      gs += __shfl_xor(gs, 16); gs += __shfl_xor(gs, 32);
      bs += __shfl_xor(bs, 16); bs += __shfl_xor(bs, 32);
      if ((lane >> 4) == 0) {
        Gpart[rb * 64 + o] = gs;
        Bpart[rb * 64 + o] = bs;
      }
    }
    return;
  }

  // ---- frs path
  int bt = blockIdx.x - 128;     // 0..255
  int b0 = bt * 8;
  {
    int row = tid >> 6, c4 = (tid & 63) * 4;
    float4 x = *(const float4*)&X[(size_t)(b0 + row) * 256 + c4];
    *(float4*)&Xs[row][c4] = x;
    uint2 p;
    p.x = bfc(x.x) | ((unsigned int)bfc(x.y) << 16);
    p.y = bfc(x.z) | ((unsigned int)bfc(x.w) << 16);
    *(uint2*)&Xbf[(size_t)(b0 + row) * 256 + c4] = p;
  }
  __syncthreads();
  int r = tid & 127, h = tid >> 7;
  float acc[8] = {0.f,0.f,0.f,0.f,0.f,0.f,0.f,0.f};
  int i0 = h * 64;
#pragma unroll 4
  for (int i = i0; i < i0 + 64; i++) {
    float sg = sigmas[i * NR_ + r];
    float c  = centers[i * NR_ + r];
    float s  = 0.5f / (sg * sg) + 1e-8f;
#pragma unroll
    for (int row = 0; row < 8; row++) {
      float d = Xs[row][i] - c;
      acc[row] = fmaf(d * s, d, acc[row]);
    }
  }
#pragma unroll
  for (int row = 0; row < 8; row++) pre[h][row][r] = acc[row];
  __syncthreads();
  int wv = tid >> 6, lane = tid & 63;
  float v0 = pre[0][wv][lane]      + pre[1][wv][lane]      + pre[2][wv][lane]      + pre[3][wv][lane];
  float v1 = pre[0][wv][lane + 64] + pre[1][wv][lane + 64] + pre[2][wv][lane + 64] + pre[3][wv][lane + 64];
  v0 *= -(1.f / 256.f);
  v1 *= -(1.f / 256.f);
  float m = fmaxf(v0, v1);
  for (int st = 32; st; st >>= 1) m = fmaxf(m, __shfl_xor(m, st));
  float e0 = __expf(v0 - m), e1 = __expf(v1 - m);
  float s = e0 + e1;
  for (int st = 32; st; st >>= 1) s += __shfl_xor(s, st);
  float invs = 1.f / s;
  float f0 = e0 * invs, f1 = e1 * invs;
  int b = b0 + wv;
  frs[(size_t)b * 128 + lane]      = f0;
  frs[(size_t)b * 128 + 64 + lane] = f1;
  float q = f0 * f0 + f1 * f1;
  for (int st = 32; st; st >>= 1) q += __shfl_xor(q, st);
  float sx = 0.f, sx2 = 0.f;
#pragma unroll
  for (int j = 0; j < 4; j++) {
    float x = Xs[wv][lane * 4 + j];
    sx += x; sx2 = fmaf(x, x, sx2);
  }
  for (int st = 32; st; st >>= 1) { sx += __shfl_xor(sx, st); sx2 += __shfl_xor(sx2, st); }
  if (lane == 0) {
    float mu  = (sx + 1.f) / (float)D_;
    float msq = q * (sx2 + 1.f) / (float)D_;
    float var = msq - mu * mu;
    float rs  = rsqrtf(var + 1e-5f);
    rstdO[b] = rs;
    murO[b]  = mu * rs;
  }
}

// ================= Kernel B: barrier-free MFMA GEMM (blocks 0..511) + G/Bb/Wtail finish (block 512)
// gemm block: 64 rows x 64 cols x 8 rules. 4 waves: wr=w&1 (32-row half), wc=w>>1 (32-col half).
// B-fragments read DIRECTLY from global Bpack (already in per-lane fragment order).
// Linear block id = bt*16+ks -> id%8 == ks%8: all 16 bt-blocks of one ks share an XCD (L2 slice reuse).
__global__ __launch_bounds__(256) void gemm_kernel(
    const unsigned short* __restrict__ Xbf, const unsigned short* __restrict__ Bpack,
    const float* __restrict__ frs, float* __restrict__ Spart,
    const float* __restrict__ W, const float* __restrict__ gamma,
    const float* __restrict__ beta, const float* __restrict__ bias,
    const float* __restrict__ Gpart, const float* __restrict__ Bpart,
    float* __restrict__ G, float* __restrict__ Bb, float* __restrict__ Wtail) {
  __shared__ float frs_s[64][9];
  __shared__ float rg[4][64], rb2[4][64];
  int tid = threadIdx.x;

  if (blockIdx.x == 512) {      // ---- finalize G, Bb, Wtail (runs concurrent with gemm)
    int o = tid & 63, ch = tid >> 6;
    float gs = 0.f, bs = 0.f;
    for (int j = ch; j < 1024; j += 4) {
      gs += Gpart[j * 64 + o];
      bs += Bpart[j * 64 + o];
    }
    rg[ch][o] = gs; rb2[ch][o] = bs;
    __syncthreads();
    if (ch == 0) {
      float gsum = rg[0][o] + rg[1][o] + rg[2][o] + rg[3][o];
      float bsum = rb2[0][o] + rb2[1][o] + rb2[2][o] + rb2[3][o];
      for (int r = 0; r < NR_; r++) {
        int d = XP_ + r;
        float wt = W[(size_t)o * D_ + d];
        float gt = wt * gamma[d];
        Wtail[r * OUT_ + o] = gt;
        gsum += gt;
        bsum += wt * beta[d];
      }
      G[o] = gsum; Bb[o] = bsum + bias[o];
    }
    return;
  }

  int ks = blockIdx.x & 15, bt = blockIdx.x >> 4;   // ks-minor => XCD-local Bpack slice
  int lane = tid & 63, w = tid >> 6, wr = w & 1, wc = w >> 1;

  for (int idx = tid; idx < 64 * 8; idx += 256) {
    int row = idx >> 3, rr = idx & 7;
    frs_s[row][rr] = frs[(size_t)(bt * 64 + row) * NR_ + ks * 8 + rr];
  }

  // X fragments in registers, reused across all 8 rules
  s16x8 xf[2][8];
  int browbase = bt * 64 + wr * 32;
#pragma unroll
  for (int rf = 0; rf < 2; rf++) {
    const unsigned short* xp = Xbf + (size_t)(browbase + rf * 16 + (lane & 15)) * 256 + (lane >> 4) * 8;
#pragma unroll
    for (int kc = 0; kc < 8; kc++)
      xf[rf][kc] = *(const s16x8*)(xp + kc * 32);
  }
  __syncthreads();   // frs_s ready (only barrier in the kernel)

  f32x4 S00 = {0.f,0.f,0.f,0.f}, S01 = S00, S10 = S00, S11 = S00;
  const s16x8* bp = (const s16x8*)Bpack;

  for (int rr = 0; rr < 8; rr++) {
    size_t fb = (size_t)((ks * 8 + rr) * 8) * 4 * 64;   // rule base fragment index
    f32x4 P00 = {0.f,0.f,0.f,0.f}, P01 = P00, P10 = P00, P11 = P00;
#pragma unroll
    for (int kc = 0; kc < 8; kc++) {
      s16x8 bf0 = bp[fb + (size_t)(kc * 4 + wc * 2 + 0) * 64 + lane];
      s16x8 bf1 = bp[fb + (size_t)(kc * 4 + wc * 2 + 1) * 64 + lane];
      P00 = __builtin_amdgcn_mfma_f32_16x16x32_bf16(xf[0][kc], bf0, P00, 0, 0, 0);
      P10 = __builtin_amdgcn_mfma_f32_16x16x32_bf16(xf[1][kc], bf0, P10, 0, 0, 0);
      P01 = __builtin_amdgcn_mfma_f32_16x16x32_bf16(xf[0][kc], bf1, P01, 0, 0, 0);
      P11 = __builtin_amdgcn_mfma_f32_16x16x32_bf16(xf[1][kc], bf1, P11, 0, 0, 0);
    }
#pragma unroll
    for (int q = 0; q < 4; q++) {
      float fv0 = frs_s[wr * 32 + 0  + (lane >> 4) * 4 + q][rr];
      float fv1 = frs_s[wr * 32 + 16 + (lane >> 4) * 4 + q][rr];
      S00[q] += fv0 * P00[q];  S01[q] += fv0 * P01[q];
      S10[q] += fv1 * P10[q];  S11[q] += fv1 * P11[q];
    }
  }

#pragma unroll
  for (int q = 0; q < 4; q++) {
    int row0 = browbase + 0  + (lane >> 4) * 4 + q;
    int row1 = browbase + 16 + (lane >> 4) * 4 + q;
    int o0 = wc * 32 + (lane & 15);
    Spart[((size_t)ks * B_ + row0) * OUT_ + o0]      = S00[q];
    Spart[((size_t)ks * B_ + row0) * OUT_ + o0 + 16] = S01[q];
    Spart[((size_t)ks * B_ + row1) * OUT_ + o0]      = S10[q];
    Spart[((size_t)ks * B_ + row1) * OUT_ + o0 + 16] = S11[q];
  }
}

// ================= Kernel C: sum K-split partials + tail GEMV + LN affine
__global__ __launch_bounds__(256) void epilogue_kernel(
    const float* __restrict__ Spart, const float* __restrict__ frs,
    const float* __restrict__ Wtail, const float* __restrict__ rstd,
    const float* __restrict__ mur, const float* __restrict__ G,
    const float* __restrict__ Bb, float* __restrict__ out) {
  int bt = blockIdx.x;
  int tid = threadIdx.x;
  __shared__ float Wt[128 * 64];
  __shared__ float fr_s[8][128];
  for (int idx = tid; idx < 128 * 64; idx += 256) Wt[idx] = Wtail[idx];
  for (int idx = tid; idx < 8 * 128; idx += 256) {
    int row = idx >> 7, r = idx & 127;
    fr_s[row][r] = frs[(size_t)(bt * 8 + row) * 128 + r];
  }
  __syncthreads();
  int o = tid & 63, rgp = tid >> 6;
  for (int rw = rgp; rw < 8; rw += 4) {
    int b = bt * 8 + rw;
    float s = 0.f;
#pragma unroll
    for (int ksi = 0; ksi < KSPLIT; ksi++)
      s += Spart[((size_t)ksi * B_ + b) * OUT_ + o];
    float t = 0.f;
#pragma unroll 8
    for (int r = 0; r < 128; r++)
      t = fmaf(fr_s[rw][r], Wt[r * 64 + o], t);
    out[(size_t)b * OUT_ + o] = rstd[b] * (s + t) - mur[b] * G[o] + Bb[o];
  }
}

extern "C" void kernel_launch(void* const* d_in, const int* in_sizes, int n_in,
                              void* d_out, int out_size, void* d_ws, size_t ws_size,
                              hipStream_t stream) {
  const float* X       = (const float*)d_in[0];
  const float* centers = (const float*)d_in[1];
  const float* sigmas  = (const float*)d_in[2];
  const float* gamma   = (const float*)d_in[3];
  const float* beta    = (const float*)d_in[4];
  const float* W       = (const float*)d_in[5];
  const float* bias    = (const float*)d_in[6];
  float* out = (float*)d_out;

  char* ws = (char*)d_ws;
  float* G             = (float*)(ws);                     // 256 B
  float* Bb            = (float*)(ws + 256);               // 256 B
  float* Wtail         = (float*)(ws + 512);               // 32768 B
  float* rstd          = (float*)(ws + 33280);             // 8192 B
  float* mur           = (float*)(ws + 41472);             // 8192 B
  float* frs           = (float*)(ws + 49664);             // 1 MB
  unsigned short* Xbf  = (unsigned short*)(ws + 1098240);  // 1 MB
  unsigned short* Bpack= (unsigned short*)(ws + 2146816);  // 4 MB
  float* Spart         = (float*)(ws + 6341120);           // 8 MB
  float* Gpart         = (float*)(ws + 14729728);          // 256 KB
  float* Bpart         = (float*)(ws + 14991872);          // 256 KB

  hipLaunchKernelGGL(prep_frs_kernel, dim3(384), dim3(512), 0, stream,
                     X, centers, sigmas, W, gamma, beta,
                     Bpack, Gpart, Bpart, frs, rstd, mur, Xbf);
  hipLaunchKernelGGL(gemm_kernel, dim3(513), dim3(256), 0, stream,
                     Xbf, Bpack, frs, Spart,
                     W, gamma, beta, bias, Gpart, Bpart, G, Bb, Wtail);
  hipLaunchKernelGGL(epilogue_kernel, dim3(B_ / 8), dim3(256), 0, stream,
                     Spart, frs, Wtail, rstd, mur, G, Bb, out);
}

// Round 5
// 170.942 us; speedup vs baseline: 1.0132x; 1.0132x over previous
//
#include <hip/hip_runtime.h>

// PreHTSK fused, MFMA edition v4 — 3 launches, LDS-staged (global_load_lds) GEMM,
// atomic output accumulation (no Spart round-trip).
// out[b,o] = rstd[b]*(S+T) + Bb[o] - mur[b]*G[o]
//   S = sum_r frs[b,r] * sum_i X[b,i]*gamma[r*256+i]*W[o,r*256+i]   (MFMA, A=X in regs)
//   T = sum_r frs[b,r] * Wtail[r][o]                                 (per-ks in gemm)
// LN closed-form: mu=(Sx+1)/D, E[f^2]=Q*(Sx2+1)/D, Q=sum frs^2 (sum frs = 1).

#define B_    2048
#define IN_   256
#define NR_   128
#define OUT_  64
#define D_    32896
#define XP_   32768
#define KSPLIT 16   // rule-groups; 8 rules per gemm block

typedef short s16x8 __attribute__((ext_vector_type(8)));
typedef float f32x4 __attribute__((ext_vector_type(4)));

__device__ __forceinline__ unsigned short bfc(float f) {
  union { float f; unsigned int u; } v; v.f = f;
  unsigned int r = (v.u + 0x7fffu + ((v.u >> 16) & 1u)) >> 16;  // RNE
  return (unsigned short)r;
}

__device__ __forceinline__ void gload_lds16(const void* g, void* l) {
  __builtin_amdgcn_global_load_lds(
      (const __attribute__((address_space(1))) void*)g,
      (__attribute__((address_space(3))) void*)l, 16, 0, 0);
}

// ================= Kernel A (416 blocks, 512 thr):
//   0..127   pack: Bpack fragments (bf16 gamma*W) + Gpart/Bpart partials (LDS-transposed coalesced W reads)
//   128..383 frs: firing levels + softmax + LN stats + X->bf16 (8 rows/block)
//   384..415 zero out (for gemm atomics)
__global__ __launch_bounds__(512) void prep_frs_kernel(
    const float* __restrict__ X, const float* __restrict__ centers,
    const float* __restrict__ sigmas, const float* __restrict__ W,
    const float* __restrict__ gamma, const float* __restrict__ beta,
    unsigned short* __restrict__ Bpack, float* __restrict__ Gpart,
    float* __restrict__ Bpart, float* __restrict__ frs,
    float* __restrict__ rstdO, float* __restrict__ murO,
    unsigned short* __restrict__ Xbf, float* __restrict__ out) {
  __shared__ float Wlds[64][68];      // pack path (17.4 KB)
  __shared__ float Xs[8][256];        // frs path
  __shared__ float pre[4][8][128];
  int tid = threadIdx.x;

  if (blockIdx.x >= 384) {            // ---- zero out
    int idx = (blockIdx.x - 384) * 1024 + tid;
    float4 z = {0.f, 0.f, 0.f, 0.f};
    ((float4*)out)[idx] = z;
    ((float4*)out)[idx + 512] = z;
    return;
  }

  if (blockIdx.x < 128) {             // ---- pack path
    int r = blockIdx.x;
    int lane = tid & 63, w = tid >> 6;
    int kcl = w & 1, ct = w >> 1;     // wave handles (k-half, col-tile)
    int o_f = ct * 16 + (lane & 15);
    for (int ic = 0; ic < 4; ic++) {  // 64-wide i-chunks
      // coalesced load: W[o][r*256+ic*64 .. +64) -> Wlds[o][0..64)
      for (int v = tid; v < 1024; v += 512) {
        int o = v >> 4, c4 = v & 15;
        float4 x = *(const float4*)&W[(size_t)o * D_ + r * 256 + ic * 64 + c4 * 4];
        *(float4*)&Wlds[o][c4 * 4] = x;
      }
      __syncthreads();
      int kc = ic * 2 + kcl;
      int il = kcl * 32 + (lane >> 4) * 8;
      int dg = r * 256 + ic * 64 + il;
      float4 g0  = *(const float4*)&gamma[dg];
      float4 g1  = *(const float4*)&gamma[dg + 4];
      float4 be0 = *(const float4*)&beta[dg];
      float4 be1 = *(const float4*)&beta[dg + 4];
      float4 w0 = *(const float4*)&Wlds[o_f][il];
      float4 w1 = *(const float4*)&Wlds[o_f][il + 4];
      unsigned int u[4];
      u[0] = bfc(w0.x * g0.x) | ((unsigned int)bfc(w0.y * g0.y) << 16);
      u[1] = bfc(w0.z * g0.z) | ((unsigned int)bfc(w0.w * g0.w) << 16);
      u[2] = bfc(w1.x * g1.x) | ((unsigned int)bfc(w1.y * g1.y) << 16);
      u[3] = bfc(w1.z * g1.z) | ((unsigned int)bfc(w1.w * g1.w) << 16);
      int rb = r * 8 + kc;
      *(uint4*)&Bpack[((size_t)(rb * 4 + ct) * 64 + lane) * 8] = make_uint4(u[0], u[1], u[2], u[3]);
      float gs = w0.x*g0.x + w0.y*g0.y + w0.z*g0.z + w0.w*g0.w
               + w1.x*g1.x + w1.y*g1.y + w1.z*g1.z + w1.w*g1.w;
      float bs = w0.x*be0.x + w0.y*be0.y + w0.z*be0.z + w0.w*be0.w
               + w1.x*be1.x + w1.y*be1.y + w1.z*be1.z + w1.w*be1.w;
      gs += __shfl_xor(gs, 16); gs += __shfl_xor(gs, 32);
      bs += __shfl_xor(bs, 16); bs += __shfl_xor(bs, 32);
      if ((lane >> 4) == 0) {
        Gpart[rb * 64 + o_f] = gs;
        Bpart[rb * 64 + o_f] = bs;
      }
      __syncthreads();
    }
    return;
  }

  // ---- frs path
  int bt = blockIdx.x - 128;          // 0..255
  int b0 = bt * 8;
  {
    int row = tid >> 6, c4 = (tid & 63) * 4;
    float4 x = *(const float4*)&X[(size_t)(b0 + row) * 256 + c4];
    *(float4*)&Xs[row][c4] = x;
    uint2 p;
    p.x = bfc(x.x) | ((unsigned int)bfc(x.y) << 16);
    p.y = bfc(x.z) | ((unsigned int)bfc(x.w) << 16);
    *(uint2*)&Xbf[(size_t)(b0 + row) * 256 + c4] = p;
  }
  __syncthreads();
  int r = tid & 127, h = tid >> 7;
  float acc[8] = {0.f,0.f,0.f,0.f,0.f,0.f,0.f,0.f};
  int i0 = h * 64;
#pragma unroll 4
  for (int i = i0; i < i0 + 64; i++) {
    float sg = sigmas[i * NR_ + r];
    float c  = centers[i * NR_ + r];
    float s  = 0.5f / (sg * sg) + 1e-8f;
#pragma unroll
    for (int row = 0; row < 8; row++) {
      float d = Xs[row][i] - c;
      acc[row] = fmaf(d * s, d, acc[row]);
    }
  }
#pragma unroll
  for (int row = 0; row < 8; row++) pre[h][row][r] = acc[row];
  __syncthreads();
  int wv = tid >> 6, lane = tid & 63;
  float v0 = pre[0][wv][lane]      + pre[1][wv][lane]      + pre[2][wv][lane]      + pre[3][wv][lane];
  float v1 = pre[0][wv][lane + 64] + pre[1][wv][lane + 64] + pre[2][wv][lane + 64] + pre[3][wv][lane + 64];
  v0 *= -(1.f / 256.f);
  v1 *= -(1.f / 256.f);
  float m = fmaxf(v0, v1);
  for (int st = 32; st; st >>= 1) m = fmaxf(m, __shfl_xor(m, st));
  float e0 = __expf(v0 - m), e1 = __expf(v1 - m);
  float s = e0 + e1;
  for (int st = 32; st; st >>= 1) s += __shfl_xor(s, st);
  float invs = 1.f / s;
  float f0 = e0 * invs, f1 = e1 * invs;
  int b = b0 + wv;
  frs[(size_t)b * 128 + lane]      = f0;
  frs[(size_t)b * 128 + 64 + lane] = f1;
  float q = f0 * f0 + f1 * f1;
  for (int st = 32; st; st >>= 1) q += __shfl_xor(q, st);
  float sx = 0.f, sx2 = 0.f;
#pragma unroll
  for (int j = 0; j < 4; j++) {
    float x = Xs[wv][lane * 4 + j];
    sx += x; sx2 = fmaf(x, x, sx2);
  }
  for (int st = 32; st; st >>= 1) { sx += __shfl_xor(sx, st); sx2 += __shfl_xor(sx2, st); }
  if (lane == 0) {
    float mu  = (sx + 1.f) / (float)D_;
    float msq = q * (sx2 + 1.f) / (float)D_;
    float var = msq - mu * mu;
    float rs  = rsqrtf(var + 1e-5f);
    rstdO[b] = rs;
    murO[b]  = mu * rs;
  }
}

// ================= Kernel B: MFMA GEMM, LDS double-buffer via global_load_lds.
// Blocks 0..511: (bt = id>>4, ks = id&15) 64 rows x 64 cols x 8 rules; ks-minor -> XCD-local Bpack slice.
// Block 512: finalize G/Bb (Gpart reduce + tail + bias).
__global__ __launch_bounds__(256) void gemm_kernel(
    const unsigned short* __restrict__ Xbf, const unsigned short* __restrict__ Bpack,
    const float* __restrict__ frs, const float* __restrict__ rstd,
    const float* __restrict__ W, const float* __restrict__ gamma,
    const float* __restrict__ beta, const float* __restrict__ bias,
    const float* __restrict__ Gpart, const float* __restrict__ Bpart,
    float* __restrict__ G, float* __restrict__ Bb, float* __restrict__ out) {
  __shared__ unsigned short Blds[2][16384];   // 2 x 32KB
  __shared__ float frs_s[64][9];
  __shared__ float Wt_s[8][64];
  __shared__ float rstd_s[64];
  __shared__ float redg[4][64], redb[4][64];
  int tid = threadIdx.x;

  if (blockIdx.x == 512) {      // ---- finalize G, Bb
    int o = tid & 63, ch = tid >> 6;
    float gs = 0.f, bs = 0.f;
    for (int j = ch; j < 1024; j += 4) {
      gs += Gpart[j * 64 + o];
      bs += Bpart[j * 64 + o];
    }
    for (int rr = ch; rr < NR_; rr += 4) {
      int d = XP_ + rr;
      float wt = W[(size_t)o * D_ + d];
      gs += wt * gamma[d];
      bs += wt * beta[d];
    }
    redg[ch][o] = gs; redb[ch][o] = bs;
    __syncthreads();
    if (ch == 0) {
      G[o]  = redg[0][o] + redg[1][o] + redg[2][o] + redg[3][o];
      Bb[o] = redb[0][o] + redb[1][o] + redb[2][o] + redb[3][o] + bias[o];
    }
    return;
  }

  int ks = blockIdx.x & 15, bt = blockIdx.x >> 4;
  int lane = tid & 63, w = tid >> 6, wr = w & 1, wc = w >> 1;

  for (int idx = tid; idx < 64 * 8; idx += 256) {
    int row = idx >> 3, rr = idx & 7;
    frs_s[row][rr] = frs[(size_t)(bt * 64 + row) * NR_ + ks * 8 + rr];
  }
  for (int idx = tid; idx < 512; idx += 256) {
    int rr = idx >> 6, o = idx & 63;
    int d = XP_ + ks * 8 + rr;
    Wt_s[rr][o] = W[(size_t)o * D_ + d] * gamma[d];
  }
  if (tid < 64) rstd_s[tid] = rstd[bt * 64 + tid];

  // X fragments in registers, reused across all 8 rules
  s16x8 xf[2][8];
  int browbase = bt * 64 + wr * 32;
#pragma unroll
  for (int rf = 0; rf < 2; rf++) {
    const unsigned short* xp = Xbf + (size_t)(browbase + rf * 16 + (lane & 15)) * 256 + (lane >> 4) * 8;
#pragma unroll
    for (int kc = 0; kc < 8; kc++)
      xf[rf][kc] = *(const s16x8*)(xp + kc * 32);
  }

  // stage rule 0 into buf 0 (32KB: 8 x 16B per thread, linear)
  const char* bbase = (const char*)Bpack + (size_t)ks * 8 * 32768;
  char* lbase = (char*)&Blds[0][0];
  {
#pragma unroll
    for (int p = 0; p < 8; p++)
      gload_lds16(bbase + tid * 16 + p * 4096, lbase + (tid >> 6) * 1024 + p * 4096);
  }
  __syncthreads();   // drains vmcnt(0): buf0 + frs_s/Wt_s/rstd_s ready

  f32x4 S00 = {0.f,0.f,0.f,0.f}, S01 = S00, S10 = S00, S11 = S00;

  for (int rr = 0; rr < 8; rr++) {
    if (rr < 7) {    // issue next-rule stage before compute (T3-lite)
      const char* src = bbase + (size_t)(rr + 1) * 32768;
      char* ldst = lbase + ((rr + 1) & 1) * 32768;
#pragma unroll
      for (int p = 0; p < 8; p++)
        gload_lds16(src + tid * 16 + p * 4096, ldst + (tid >> 6) * 1024 + p * 4096);
    }
    const unsigned short* bb = &Blds[rr & 1][0];
    f32x4 P00 = {0.f,0.f,0.f,0.f}, P01 = P00, P10 = P00, P11 = P00;
#pragma unroll
    for (int kc = 0; kc < 8; kc++) {
      s16x8 bf0 = *(const s16x8*)(bb + (size_t)((kc * 4 + wc * 2 + 0) * 64 + lane) * 8);
      s16x8 bf1 = *(const s16x8*)(bb + (size_t)((kc * 4 + wc * 2 + 1) * 64 + lane) * 8);
      P00 = __builtin_amdgcn_mfma_f32_16x16x32_bf16(xf[0][kc], bf0, P00, 0, 0, 0);
      P10 = __builtin_amdgcn_mfma_f32_16x16x32_bf16(xf[1][kc], bf0, P10, 0, 0, 0);
      P01 = __builtin_amdgcn_mfma_f32_16x16x32_bf16(xf[0][kc], bf1, P01, 0, 0, 0);
      P11 = __builtin_amdgcn_mfma_f32_16x16x32_bf16(xf[1][kc], bf1, P11, 0, 0, 0);
    }
#pragma unroll
    for (int q = 0; q < 4; q++) {
      float fv0 = frs_s[wr * 32 + 0  + (lane >> 4) * 4 + q][rr];
      float fv1 = frs_s[wr * 32 + 16 + (lane >> 4) * 4 + q][rr];
      S00[q] += fv0 * P00[q];  S01[q] += fv0 * P01[q];
      S10[q] += fv1 * P10[q];  S11[q] += fv1 * P11[q];
    }
    __syncthreads();   // next buffer staged (compiler emits vmcnt(0) before barrier)
  }

  // tail GEMV + rstd scale + atomic accumulate into out
  int o0 = wc * 32 + (lane & 15);
#pragma unroll
  for (int q = 0; q < 4; q++) {
    int lr0 = wr * 32 + 0  + (lane >> 4) * 4 + q;
    int lr1 = lr0 + 16;
    float t00 = 0.f, t01 = 0.f, t10 = 0.f, t11 = 0.f;
#pragma unroll
    for (int rr = 0; rr < 8; rr++) {
      float f0 = frs_s[lr0][rr], f1 = frs_s[lr1][rr];
      t00 = fmaf(f0, Wt_s[rr][o0],      t00);
      t01 = fmaf(f0, Wt_s[rr][o0 + 16], t01);
      t10 = fmaf(f1, Wt_s[rr][o0],      t10);
      t11 = fmaf(f1, Wt_s[rr][o0 + 16], t11);
    }
    float r0 = rstd_s[lr0], r1 = rstd_s[lr1];
    size_t base0 = (size_t)(bt * 64 + lr0) * OUT_;
    size_t base1 = (size_t)(bt * 64 + lr1) * OUT_;
    atomicAdd(&out[base0 + o0],      r0 * (S00[q] + t00));
    atomicAdd(&out[base0 + o0 + 16], r0 * (S01[q] + t01));
    atomicAdd(&out[base1 + o0],      r1 * (S10[q] + t10));
    atomicAdd(&out[base1 + o0 + 16], r1 * (S11[q] + t11));
  }
}

// ================= Kernel C: add the affine constant  out += Bb[o] - mur[b]*G[o]
__global__ __launch_bounds__(512) void final_kernel(
    const float* __restrict__ G, const float* __restrict__ Bb,
    const float* __restrict__ mur, float* __restrict__ out) {
  int idx = blockIdx.x * 512 + threadIdx.x;   // grid 256 -> 131072
  int b = idx >> 6, o = idx & 63;
  out[idx] += Bb[o] - mur[b] * G[o];
}

extern "C" void kernel_launch(void* const* d_in, const int* in_sizes, int n_in,
                              void* d_out, int out_size, void* d_ws, size_t ws_size,
                              hipStream_t stream) {
  const float* X       = (const float*)d_in[0];
  const float* centers = (const float*)d_in[1];
  const float* sigmas  = (const float*)d_in[2];
  const float* gamma   = (const float*)d_in[3];
  const float* beta    = (const float*)d_in[4];
  const float* W       = (const float*)d_in[5];
  const float* bias    = (const float*)d_in[6];
  float* out = (float*)d_out;

  char* ws = (char*)d_ws;
  float* G             = (float*)(ws);                     // 256 B
  float* Bb            = (float*)(ws + 256);               // 256 B
  float* rstd          = (float*)(ws + 512);               // 8 KB
  float* mur           = (float*)(ws + 8704);              // 8 KB
  float* frs           = (float*)(ws + 16896);             // 1 MB
  unsigned short* Xbf  = (unsigned short*)(ws + 1065472);  // 1 MB
  unsigned short* Bpack= (unsigned short*)(ws + 2114048);  // 4 MB
  float* Gpart         = (float*)(ws + 6308352);           // 256 KB
  float* Bpart         = (float*)(ws + 6570496);           // 256 KB (total ~6.8 MB)

  hipLaunchKernelGGL(prep_frs_kernel, dim3(416), dim3(512), 0, stream,
                     X, centers, sigmas, W, gamma, beta,
                     Bpack, Gpart, Bpart, frs, rstd, mur, Xbf, out);
  hipLaunchKernelGGL(gemm_kernel, dim3(513), dim3(256), 0, stream,
                     Xbf, Bpack, frs, rstd, W, gamma, beta, bias,
                     Gpart, Bpart, G, Bb, out);
  hipLaunchKernelGGL(final_kernel, dim3(256), dim3(512), 0, stream,
                     G, Bb, mur, out);
}

// Round 6
// 115.243 us; speedup vs baseline: 1.5029x; 1.4833x over previous
//
#include <hip/hip_runtime.h>

// PreHTSK fused, MFMA edition v5 — straggler fix: G/Bb finalize moved out of the
// gemm grid into a coalesced 64-block reduce kernel (R4/R5's gemm "87us" was one
// serial uncoalesced finalize block; the 512 MFMA blocks finish in ~us).
// out[b,o] = rstd[b]*(S+T) + Bb[o] - mur[b]*G[o]
//   S = sum_r frs[b,r] * sum_i X[b,i]*gamma[r*256+i]*W[o,r*256+i]   (MFMA, A=X in regs)
//   T = sum_r frs[b,r] * Wtail[r][o]                                 (per-ks in gemm)
// LN closed-form: mu=(Sx+1)/D, E[f^2]=Q*(Sx2+1)/D, Q=sum frs^2 (sum frs = 1).

#define B_    2048
#define IN_   256
#define NR_   128
#define OUT_  64
#define D_    32896
#define XP_   32768
#define KSPLIT 16   // rule-groups; 8 rules per gemm block

typedef short s16x8 __attribute__((ext_vector_type(8)));
typedef float f32x4 __attribute__((ext_vector_type(4)));

__device__ __forceinline__ unsigned short bfc(float f) {
  union { float f; unsigned int u; } v; v.f = f;
  unsigned int r = (v.u + 0x7fffu + ((v.u >> 16) & 1u)) >> 16;  // RNE
  return (unsigned short)r;
}

__device__ __forceinline__ void gload_lds16(const void* g, void* l) {
  __builtin_amdgcn_global_load_lds(
      (const __attribute__((address_space(1))) void*)g,
      (__attribute__((address_space(3))) void*)l, 16, 0, 0);
}

// ================= Kernel A (416 blocks, 512 thr):
//   0..127   pack: Bpack fragments (bf16 gamma*W) + Gpart/Bpart partials ([o][1024] transposed)
//   128..383 frs: firing levels + softmax + LN stats + X->bf16 (8 rows/block)
//   384..415 zero out (for gemm atomics)
__global__ __launch_bounds__(512) void prep_frs_kernel(
    const float* __restrict__ X, const float* __restrict__ centers,
    const float* __restrict__ sigmas, const float* __restrict__ W,
    const float* __restrict__ gamma, const float* __restrict__ beta,
    unsigned short* __restrict__ Bpack, float* __restrict__ Gpart,
    float* __restrict__ Bpart, float* __restrict__ frs,
    float* __restrict__ rstdO, float* __restrict__ murO,
    unsigned short* __restrict__ Xbf, float* __restrict__ out) {
  __shared__ float Wlds[64][68];      // pack path (17.4 KB)
  __shared__ float Xs[8][256];        // frs path
  __shared__ float pre[4][8][128];
  int tid = threadIdx.x;

  if (blockIdx.x >= 384) {            // ---- zero out
    int idx = (blockIdx.x - 384) * 1024 + tid;
    float4 z = {0.f, 0.f, 0.f, 0.f};
    ((float4*)out)[idx] = z;
    ((float4*)out)[idx + 512] = z;
    return;
  }

  if (blockIdx.x < 128) {             // ---- pack path
    int r = blockIdx.x;
    int lane = tid & 63, w = tid >> 6;
    int kcl = w & 1, ct = w >> 1;     // wave handles (k-half, col-tile)
    int o_f = ct * 16 + (lane & 15);
    for (int ic = 0; ic < 4; ic++) {  // 64-wide i-chunks
      // coalesced load: W[o][r*256+ic*64 .. +64) -> Wlds[o][0..64)
      for (int v = tid; v < 1024; v += 512) {
        int o = v >> 4, c4 = v & 15;
        float4 x = *(const float4*)&W[(size_t)o * D_ + r * 256 + ic * 64 + c4 * 4];
        *(float4*)&Wlds[o][c4 * 4] = x;
      }
      __syncthreads();
      int kc = ic * 2 + kcl;
      int il = kcl * 32 + (lane >> 4) * 8;
      int dg = r * 256 + ic * 64 + il;
      float4 g0  = *(const float4*)&gamma[dg];
      float4 g1  = *(const float4*)&gamma[dg + 4];
      float4 be0 = *(const float4*)&beta[dg];
      float4 be1 = *(const float4*)&beta[dg + 4];
      float4 w0 = *(const float4*)&Wlds[o_f][il];
      float4 w1 = *(const float4*)&Wlds[o_f][il + 4];
      unsigned int u[4];
      u[0] = bfc(w0.x * g0.x) | ((unsigned int)bfc(w0.y * g0.y) << 16);
      u[1] = bfc(w0.z * g0.z) | ((unsigned int)bfc(w0.w * g0.w) << 16);
      u[2] = bfc(w1.x * g1.x) | ((unsigned int)bfc(w1.y * g1.y) << 16);
      u[3] = bfc(w1.z * g1.z) | ((unsigned int)bfc(w1.w * g1.w) << 16);
      int rb = r * 8 + kc;
      *(uint4*)&Bpack[((size_t)(rb * 4 + ct) * 64 + lane) * 8] = make_uint4(u[0], u[1], u[2], u[3]);
      float gs = w0.x*g0.x + w0.y*g0.y + w0.z*g0.z + w0.w*g0.w
               + w1.x*g1.x + w1.y*g1.y + w1.z*g1.z + w1.w*g1.w;
      float bs = w0.x*be0.x + w0.y*be0.y + w0.z*be0.z + w0.w*be0.w
               + w1.x*be1.x + w1.y*be1.y + w1.z*be1.z + w1.w*be1.w;
      gs += __shfl_xor(gs, 16); gs += __shfl_xor(gs, 32);
      bs += __shfl_xor(bs, 16); bs += __shfl_xor(bs, 32);
      if ((lane >> 4) == 0) {         // transposed: [o][rb] for coalesced reduce
        Gpart[(size_t)o_f * 1024 + rb] = gs;
        Bpart[(size_t)o_f * 1024 + rb] = bs;
      }
      __syncthreads();
    }
    return;
  }

  // ---- frs path
  int bt = blockIdx.x - 128;          // 0..255
  int b0 = bt * 8;
  {
    int row = tid >> 6, c4 = (tid & 63) * 4;
    float4 x = *(const float4*)&X[(size_t)(b0 + row) * 256 + c4];
    *(float4*)&Xs[row][c4] = x;
    uint2 p;
    p.x = bfc(x.x) | ((unsigned int)bfc(x.y) << 16);
    p.y = bfc(x.z) | ((unsigned int)bfc(x.w) << 16);
    *(uint2*)&Xbf[(size_t)(b0 + row) * 256 + c4] = p;
  }
  __syncthreads();
  int r = tid & 127, h = tid >> 7;
  float acc[8] = {0.f,0.f,0.f,0.f,0.f,0.f,0.f,0.f};
  int i0 = h * 64;
#pragma unroll 4
  for (int i = i0; i < i0 + 64; i++) {
    float sg = sigmas[i * NR_ + r];
    float c  = centers[i * NR_ + r];
    float s  = 0.5f / (sg * sg) + 1e-8f;
#pragma unroll
    for (int row = 0; row < 8; row++) {
      float d = Xs[row][i] - c;
      acc[row] = fmaf(d * s, d, acc[row]);
    }
  }
#pragma unroll
  for (int row = 0; row < 8; row++) pre[h][row][r] = acc[row];
  __syncthreads();
  int wv = tid >> 6, lane = tid & 63;
  float v0 = pre[0][wv][lane]      + pre[1][wv][lane]      + pre[2][wv][lane]      + pre[3][wv][lane];
  float v1 = pre[0][wv][lane + 64] + pre[1][wv][lane + 64] + pre[2][wv][lane + 64] + pre[3][wv][lane + 64];
  v0 *= -(1.f / 256.f);
  v1 *= -(1.f / 256.f);
  float m = fmaxf(v0, v1);
  for (int st = 32; st; st >>= 1) m = fmaxf(m, __shfl_xor(m, st));
  float e0 = __expf(v0 - m), e1 = __expf(v1 - m);
  float s = e0 + e1;
  for (int st = 32; st; st >>= 1) s += __shfl_xor(s, st);
  float invs = 1.f / s;
  float f0 = e0 * invs, f1 = e1 * invs;
  int b = b0 + wv;
  frs[(size_t)b * 128 + lane]      = f0;
  frs[(size_t)b * 128 + 64 + lane] = f1;
  float q = f0 * f0 + f1 * f1;
  for (int st = 32; st; st >>= 1) q += __shfl_xor(q, st);
  float sx = 0.f, sx2 = 0.f;
#pragma unroll
  for (int j = 0; j < 4; j++) {
    float x = Xs[wv][lane * 4 + j];
    sx += x; sx2 = fmaf(x, x, sx2);
  }
  for (int st = 32; st; st >>= 1) { sx += __shfl_xor(sx, st); sx2 += __shfl_xor(sx2, st); }
  if (lane == 0) {
    float mu  = (sx + 1.f) / (float)D_;
    float msq = q * (sx2 + 1.f) / (float)D_;
    float var = msq - mu * mu;
    float rs  = rsqrtf(var + 1e-5f);
    rstdO[b] = rs;
    murO[b]  = mu * rs;
  }
}

// ================= Kernel B: G/Bb finalize — 64 blocks (one per o), coalesced.
__global__ __launch_bounds__(256) void reduce_kernel(
    const float* __restrict__ W, const float* __restrict__ gamma,
    const float* __restrict__ beta, const float* __restrict__ bias,
    const float* __restrict__ Gpart, const float* __restrict__ Bpart,
    float* __restrict__ G, float* __restrict__ Bb) {
  int o = blockIdx.x, t = threadIdx.x;
  __shared__ float rg[256], rb[256];
  float gs = 0.f, bs = 0.f;
  for (int j = t; j < 1024; j += 256) {     // coalesced: Gpart[o][j]
    gs += Gpart[(size_t)o * 1024 + j];
    bs += Bpart[(size_t)o * 1024 + j];
  }
  if (t < 128) {                            // tail: contiguous over t
    int d = XP_ + t;
    float wt = W[(size_t)o * D_ + d];
    gs += wt * gamma[d];
    bs += wt * beta[d];
  }
  rg[t] = gs; rb[t] = bs;
  __syncthreads();
  for (int st = 128; st > 0; st >>= 1) {
    if (t < st) { rg[t] += rg[t + st]; rb[t] += rb[t + st]; }
    __syncthreads();
  }
  if (t == 0) { G[o] = rg[0]; Bb[o] = rb[0] + bias[o]; }
}

// ================= Kernel C: MFMA GEMM, LDS double-buffer via global_load_lds.
// 512 blocks: (bt = id>>4, ks = id&15) 64 rows x 64 cols x 8 rules.
__global__ __launch_bounds__(256) void gemm_kernel(
    const unsigned short* __restrict__ Xbf, const unsigned short* __restrict__ Bpack,
    const float* __restrict__ frs, const float* __restrict__ rstd,
    const float* __restrict__ W, const float* __restrict__ gamma,
    float* __restrict__ out) {
  __shared__ unsigned short Blds[2][16384];   // 2 x 32KB
  __shared__ float frs_s[64][9];
  __shared__ float Wt_s[8][64];
  __shared__ float rstd_s[64];
  int tid = threadIdx.x;

  int ks = blockIdx.x & 15, bt = blockIdx.x >> 4;
  int lane = tid & 63, w = tid >> 6, wr = w & 1, wc = w >> 1;

  for (int idx = tid; idx < 64 * 8; idx += 256) {
    int row = idx >> 3, rr = idx & 7;
    frs_s[row][rr] = frs[(size_t)(bt * 64 + row) * NR_ + ks * 8 + rr];
  }
  for (int idx = tid; idx < 512; idx += 256) {
    int rr = idx >> 6, o = idx & 63;
    int d = XP_ + ks * 8 + rr;
    Wt_s[rr][o] = W[(size_t)o * D_ + d] * gamma[d];
  }
  if (tid < 64) rstd_s[tid] = rstd[bt * 64 + tid];

  // X fragments in registers, reused across all 8 rules
  s16x8 xf[2][8];
  int browbase = bt * 64 + wr * 32;
#pragma unroll
  for (int rf = 0; rf < 2; rf++) {
    const unsigned short* xp = Xbf + (size_t)(browbase + rf * 16 + (lane & 15)) * 256 + (lane >> 4) * 8;
#pragma unroll
    for (int kc = 0; kc < 8; kc++)
      xf[rf][kc] = *(const s16x8*)(xp + kc * 32);
  }

  // stage rule 0 into buf 0 (32KB: 8 x 16B per thread, linear)
  const char* bbase = (const char*)Bpack + (size_t)ks * 8 * 32768;
  char* lbase = (char*)&Blds[0][0];
  {
#pragma unroll
    for (int p = 0; p < 8; p++)
      gload_lds16(bbase + tid * 16 + p * 4096, lbase + (tid >> 6) * 1024 + p * 4096);
  }
  __syncthreads();   // drains vmcnt(0): buf0 + frs_s/Wt_s/rstd_s ready

  f32x4 S00 = {0.f,0.f,0.f,0.f}, S01 = S00, S10 = S00, S11 = S00;

  for (int rr = 0; rr < 8; rr++) {
    if (rr < 7) {    // issue next-rule stage before compute
      const char* src = bbase + (size_t)(rr + 1) * 32768;
      char* ldst = lbase + ((rr + 1) & 1) * 32768;
#pragma unroll
      for (int p = 0; p < 8; p++)
        gload_lds16(src + tid * 16 + p * 4096, ldst + (tid >> 6) * 1024 + p * 4096);
    }
    const unsigned short* bb = &Blds[rr & 1][0];
    f32x4 P00 = {0.f,0.f,0.f,0.f}, P01 = P00, P10 = P00, P11 = P00;
#pragma unroll
    for (int kc = 0; kc < 8; kc++) {
      s16x8 bf0 = *(const s16x8*)(bb + (size_t)((kc * 4 + wc * 2 + 0) * 64 + lane) * 8);
      s16x8 bf1 = *(const s16x8*)(bb + (size_t)((kc * 4 + wc * 2 + 1) * 64 + lane) * 8);
      P00 = __builtin_amdgcn_mfma_f32_16x16x32_bf16(xf[0][kc], bf0, P00, 0, 0, 0);
      P10 = __builtin_amdgcn_mfma_f32_16x16x32_bf16(xf[1][kc], bf0, P10, 0, 0, 0);
      P01 = __builtin_amdgcn_mfma_f32_16x16x32_bf16(xf[0][kc], bf1, P01, 0, 0, 0);
      P11 = __builtin_amdgcn_mfma_f32_16x16x32_bf16(xf[1][kc], bf1, P11, 0, 0, 0);
    }
#pragma unroll
    for (int q = 0; q < 4; q++) {
      float fv0 = frs_s[wr * 32 + 0  + (lane >> 4) * 4 + q][rr];
      float fv1 = frs_s[wr * 32 + 16 + (lane >> 4) * 4 + q][rr];
      S00[q] += fv0 * P00[q];  S01[q] += fv0 * P01[q];
      S10[q] += fv1 * P10[q];  S11[q] += fv1 * P11[q];
    }
    __syncthreads();   // next buffer staged
  }

  // tail GEMV + rstd scale + atomic accumulate into out
  int o0 = wc * 32 + (lane & 15);
#pragma unroll
  for (int q = 0; q < 4; q++) {
    int lr0 = wr * 32 + 0  + (lane >> 4) * 4 + q;
    int lr1 = lr0 + 16;
    float t00 = 0.f, t01 = 0.f, t10 = 0.f, t11 = 0.f;
#pragma unroll
    for (int rr = 0; rr < 8; rr++) {
      float f0 = frs_s[lr0][rr], f1 = frs_s[lr1][rr];
      t00 = fmaf(f0, Wt_s[rr][o0],      t00);
      t01 = fmaf(f0, Wt_s[rr][o0 + 16], t01);
      t10 = fmaf(f1, Wt_s[rr][o0],      t10);
      t11 = fmaf(f1, Wt_s[rr][o0 + 16], t11);
    }
    float r0 = rstd_s[lr0], r1 = rstd_s[lr1];
    size_t base0 = (size_t)(bt * 64 + lr0) * OUT_;
    size_t base1 = (size_t)(bt * 64 + lr1) * OUT_;
    atomicAdd(&out[base0 + o0],      r0 * (S00[q] + t00));
    atomicAdd(&out[base0 + o0 + 16], r0 * (S01[q] + t01));
    atomicAdd(&out[base1 + o0],      r1 * (S10[q] + t10));
    atomicAdd(&out[base1 + o0 + 16], r1 * (S11[q] + t11));
  }
}

// ================= Kernel D: add the affine constant  out += Bb[o] - mur[b]*G[o]
__global__ __launch_bounds__(512) void final_kernel(
    const float* __restrict__ G, const float* __restrict__ Bb,
    const float* __restrict__ mur, float* __restrict__ out) {
  int idx = blockIdx.x * 512 + threadIdx.x;   // grid 256 -> 131072
  int b = idx >> 6, o = idx & 63;
  out[idx] += Bb[o] - mur[b] * G[o];
}

extern "C" void kernel_launch(void* const* d_in, const int* in_sizes, int n_in,
                              void* d_out, int out_size, void* d_ws, size_t ws_size,
                              hipStream_t stream) {
  const float* X       = (const float*)d_in[0];
  const float* centers = (const float*)d_in[1];
  const float* sigmas  = (const float*)d_in[2];
  const float* gamma   = (const float*)d_in[3];
  const float* beta    = (const float*)d_in[4];
  const float* W       = (const float*)d_in[5];
  const float* bias    = (const float*)d_in[6];
  float* out = (float*)d_out;

  char* ws = (char*)d_ws;
  float* G             = (float*)(ws);                     // 256 B
  float* Bb            = (float*)(ws + 256);               // 256 B
  float* rstd          = (float*)(ws + 512);               // 8 KB
  float* mur           = (float*)(ws + 8704);              // 8 KB
  float* frs           = (float*)(ws + 16896);             // 1 MB
  unsigned short* Xbf  = (unsigned short*)(ws + 1065472);  // 1 MB
  unsigned short* Bpack= (unsigned short*)(ws + 2114048);  // 4 MB
  float* Gpart         = (float*)(ws + 6308352);           // 256 KB
  float* Bpart         = (float*)(ws + 6570496);           // 256 KB (total ~6.8 MB)

  hipLaunchKernelGGL(prep_frs_kernel, dim3(416), dim3(512), 0, stream,
                     X, centers, sigmas, W, gamma, beta,
                     Bpack, Gpart, Bpart, frs, rstd, mur, Xbf, out);
  hipLaunchKernelGGL(reduce_kernel, dim3(OUT_), dim3(256), 0, stream,
                     W, gamma, beta, bias, Gpart, Bpart, G, Bb);
  hipLaunchKernelGGL(gemm_kernel, dim3(512), dim3(256), 0, stream,
                     Xbf, Bpack, frs, rstd, W, gamma, out);
  hipLaunchKernelGGL(final_kernel, dim3(256), dim3(512), 0, stream,
                     G, Bb, mur, out);
}

// Round 8
// 114.722 us; speedup vs baseline: 1.5097x; 1.0045x over previous
//
#include <hip/hip_runtime.h>

// PreHTSK fused, MFMA edition v6 — 3 launches; XCD-local atomics (bt-minor block
// mapping); affine constant folded into gemm ks==0 blocks; 256-block pack path;
// Wtail precomputed.  (Resubmission: R7 bench was an infra failure, kernel unmeasured.)
// out[b,o] = rstd[b]*(S+T) + Bb[o] - mur[b]*G[o]
//   S = sum_r frs[b,r] * sum_i X[b,i]*gamma[r*256+i]*W[o,r*256+i]   (MFMA, A=X in regs)
//   T = sum_r frs[b,r] * Wtail[r][o]
// LN closed-form: mu=(Sx+1)/D, E[f^2]=Q*(Sx2+1)/D, Q=sum frs^2 (sum frs = 1).

#define B_    2048
#define IN_   256
#define NR_   128
#define OUT_  64
#define D_    32896
#define XP_   32768
#define KSPLIT 16   // rule-groups; 8 rules per gemm block

typedef short s16x8 __attribute__((ext_vector_type(8)));
typedef float f32x4 __attribute__((ext_vector_type(4)));

__device__ __forceinline__ unsigned short bfc(float f) {
  union { float f; unsigned int u; } v; v.f = f;
  unsigned int r = (v.u + 0x7fffu + ((v.u >> 16) & 1u)) >> 16;  // RNE
  return (unsigned short)r;
}

__device__ __forceinline__ void gload_lds16(const void* g, void* l) {
  __builtin_amdgcn_global_load_lds(
      (const __attribute__((address_space(1))) void*)g,
      (__attribute__((address_space(3))) void*)l, 16, 0, 0);
}

// ================= Kernel A (544 blocks, 512 thr):
//   0..255   pack: r = bid>>1, ic-half = bid&1. Bpack fragments (bf16 gamma*W),
//            Gpart/Bpart partials ([o][1024] transposed), Wtail (half==1).
//   256..511 frs: firing levels + softmax + LN stats + X->bf16 (8 rows/block)
//   512..543 zero out (for gemm atomics)
__global__ __launch_bounds__(512) void prep_frs_kernel(
    const float* __restrict__ X, const float* __restrict__ centers,
    const float* __restrict__ sigmas, const float* __restrict__ W,
    const float* __restrict__ gamma, const float* __restrict__ beta,
    unsigned short* __restrict__ Bpack, float* __restrict__ Gpart,
    float* __restrict__ Bpart, float* __restrict__ Wtail,
    float* __restrict__ frs, float* __restrict__ rstdO,
    float* __restrict__ murO, unsigned short* __restrict__ Xbf,
    float* __restrict__ out) {
  __shared__ float Wlds[64][68];      // pack path
  __shared__ float Xs[8][256];        // frs path
  __shared__ float pre[4][8][128];
  int tid = threadIdx.x;

  if (blockIdx.x >= 512) {            // ---- zero out
    int idx = (blockIdx.x - 512) * 1024 + tid;
    float4 z = {0.f, 0.f, 0.f, 0.f};
    ((float4*)out)[idx] = z;
    ((float4*)out)[idx + 512] = z;
    return;
  }

  if (blockIdx.x < 256) {             // ---- pack path
    int r = blockIdx.x >> 1, half = blockIdx.x & 1;
    int lane = tid & 63, w = tid >> 6;
    int kcl = w & 1, ct = w >> 1;     // wave handles (k-half, col-tile)
    int o_f = ct * 16 + (lane & 15);
    if (half == 1 && tid < 64) {      // Wtail[r][o] (scattered, 64 loads)
      int d = XP_ + r;
      Wtail[r * 64 + tid] = W[(size_t)tid * D_ + d] * gamma[d];
    }
    for (int ici = 0; ici < 2; ici++) {
      int ic = half * 2 + ici;
      // coalesced: W[o][r*256+ic*64 .. +64) -> Wlds[o][0..64)
      for (int v = tid; v < 1024; v += 512) {
        int o = v >> 4, c4 = v & 15;
        float4 x = *(const float4*)&W[(size_t)o * D_ + r * 256 + ic * 64 + c4 * 4];
        *(float4*)&Wlds[o][c4 * 4] = x;
      }
      __syncthreads();
      int kc = ic * 2 + kcl;
      int il = kcl * 32 + (lane >> 4) * 8;
      int dg = r * 256 + ic * 64 + il;
      float4 g0  = *(const float4*)&gamma[dg];
      float4 g1  = *(const float4*)&gamma[dg + 4];
      float4 be0 = *(const float4*)&beta[dg];
      float4 be1 = *(const float4*)&beta[dg + 4];
      float4 w0 = *(const float4*)&Wlds[o_f][il];
      float4 w1 = *(const float4*)&Wlds[o_f][il + 4];
      unsigned int u[4];
      u[0] = bfc(w0.x * g0.x) | ((unsigned int)bfc(w0.y * g0.y) << 16);
      u[1] = bfc(w0.z * g0.z) | ((unsigned int)bfc(w0.w * g0.w) << 16);
      u[2] = bfc(w1.x * g1.x) | ((unsigned int)bfc(w1.y * g1.y) << 16);
      u[3] = bfc(w1.z * g1.z) | ((unsigned int)bfc(w1.w * g1.w) << 16);
      int rb = r * 8 + kc;
      *(uint4*)&Bpack[((size_t)(rb * 4 + ct) * 64 + lane) * 8] = make_uint4(u[0], u[1], u[2], u[3]);
      float gs = w0.x*g0.x + w0.y*g0.y + w0.z*g0.z + w0.w*g0.w
               + w1.x*g1.x + w1.y*g1.y + w1.z*g1.z + w1.w*g1.w;
      float bs = w0.x*be0.x + w0.y*be0.y + w0.z*be0.z + w0.w*be0.w
               + w1.x*be1.x + w1.y*be1.y + w1.z*be1.z + w1.w*be1.w;
      gs += __shfl_xor(gs, 16); gs += __shfl_xor(gs, 32);
      bs += __shfl_xor(bs, 16); bs += __shfl_xor(bs, 32);
      if ((lane >> 4) == 0) {         // transposed: [o][rb] for coalesced reduce
        Gpart[(size_t)o_f * 1024 + rb] = gs;
        Bpart[(size_t)o_f * 1024 + rb] = bs;
      }
      __syncthreads();
    }
    return;
  }

  // ---- frs path
  int bt = blockIdx.x - 256;          // 0..255
  int b0 = bt * 8;
  {
    int row = tid >> 6, c4 = (tid & 63) * 4;
    float4 x = *(const float4*)&X[(size_t)(b0 + row) * 256 + c4];
    *(float4*)&Xs[row][c4] = x;
    uint2 p;
    p.x = bfc(x.x) | ((unsigned int)bfc(x.y) << 16);
    p.y = bfc(x.z) | ((unsigned int)bfc(x.w) << 16);
    *(uint2*)&Xbf[(size_t)(b0 + row) * 256 + c4] = p;
  }
  __syncthreads();
  int r = tid & 127, h = tid >> 7;
  float acc[8] = {0.f,0.f,0.f,0.f,0.f,0.f,0.f,0.f};
  int i0 = h * 64;
#pragma unroll 4
  for (int i = i0; i < i0 + 64; i++) {
    float sg = sigmas[i * NR_ + r];
    float c  = centers[i * NR_ + r];
    float s  = __fdividef(0.5f, sg * sg) + 1e-8f;
#pragma unroll
    for (int row = 0; row < 8; row++) {
      float d = Xs[row][i] - c;
      acc[row] = fmaf(d * s, d, acc[row]);
    }
  }
#pragma unroll
  for (int row = 0; row < 8; row++) pre[h][row][r] = acc[row];
  __syncthreads();
  int wv = tid >> 6, lane = tid & 63;
  float v0 = pre[0][wv][lane]      + pre[1][wv][lane]      + pre[2][wv][lane]      + pre[3][wv][lane];
  float v1 = pre[0][wv][lane + 64] + pre[1][wv][lane + 64] + pre[2][wv][lane + 64] + pre[3][wv][lane + 64];
  v0 *= -(1.f / 256.f);
  v1 *= -(1.f / 256.f);
  float m = fmaxf(v0, v1);
  for (int st = 32; st; st >>= 1) m = fmaxf(m, __shfl_xor(m, st));
  float e0 = __expf(v0 - m), e1 = __expf(v1 - m);
  float s = e0 + e1;
  for (int st = 32; st; st >>= 1) s += __shfl_xor(s, st);
  float invs = 1.f / s;
  float f0 = e0 * invs, f1 = e1 * invs;
  int b = b0 + wv;
  frs[(size_t)b * 128 + lane]      = f0;
  frs[(size_t)b * 128 + 64 + lane] = f1;
  float q = f0 * f0 + f1 * f1;
  for (int st = 32; st; st >>= 1) q += __shfl_xor(q, st);
  float sx = 0.f, sx2 = 0.f;
#pragma unroll
  for (int j = 0; j < 4; j++) {
    float x = Xs[wv][lane * 4 + j];
    sx += x; sx2 = fmaf(x, x, sx2);
  }
  for (int st = 32; st; st >>= 1) { sx += __shfl_xor(sx, st); sx2 += __shfl_xor(sx2, st); }
  if (lane == 0) {
    float mu  = (sx + 1.f) / (float)D_;
    float msq = q * (sx2 + 1.f) / (float)D_;
    float var = msq - mu * mu;
    float rs  = rsqrtf(var + 1e-5f);
    rstdO[b] = rs;
    murO[b]  = mu * rs;
  }
}

// ================= Kernel B: G/Bb finalize — 64 blocks (one per o), coalesced.
__global__ __launch_bounds__(256) void reduce_kernel(
    const float* __restrict__ W, const float* __restrict__ gamma,
    const float* __restrict__ beta, const float* __restrict__ bias,
    const float* __restrict__ Gpart, const float* __restrict__ Bpart,
    float* __restrict__ G, float* __restrict__ Bb) {
  int o = blockIdx.x, t = threadIdx.x;
  __shared__ float rg[256], rb[256];
  float gs = 0.f, bs = 0.f;
  for (int j = t; j < 1024; j += 256) {     // coalesced: Gpart[o][j]
    gs += Gpart[(size_t)o * 1024 + j];
    bs += Bpart[(size_t)o * 1024 + j];
  }
  if (t < 128) {                            // tail: contiguous over t
    int d = XP_ + t;
    float wt = W[(size_t)o * D_ + d];
    gs += wt * gamma[d];
    bs += wt * beta[d];
  }
  rg[t] = gs; rb[t] = bs;
  __syncthreads();
  for (int st = 128; st > 0; st >>= 1) {
    if (t < st) { rg[t] += rg[t + st]; rb[t] += rb[t + st]; }
    __syncthreads();
  }
  if (t == 0) { G[o] = rg[0]; Bb[o] = rb[0] + bias[o]; }
}

// ================= Kernel C: MFMA GEMM, LDS dbuf via global_load_lds.
// 512 blocks, bt-MINOR: bt = id&31, ks = id>>5  =>  id%8 = bt%8: all 16 ks-blocks
// of one bt share an XCD -> out-atomics stay in one L2 (no cross-XCD bouncing).
// ks==0 blocks also add the affine constant Bb[o] - mur[b]*G[o].
__global__ __launch_bounds__(256) void gemm_kernel(
    const unsigned short* __restrict__ Xbf, const unsigned short* __restrict__ Bpack,
    const float* __restrict__ frs, const float* __restrict__ rstd,
    const float* __restrict__ Wtail, const float* __restrict__ G,
    const float* __restrict__ Bb, const float* __restrict__ mur,
    float* __restrict__ out) {
  __shared__ unsigned short Blds[2][16384];   // 2 x 32KB
  __shared__ float frs_s[64][9];
  __shared__ float Wt_s[8][64];
  __shared__ float rstd_s[64];
  __shared__ float G_s[64], Bb_s[64], mur_s[64];
  int tid = threadIdx.x;

  int bt = blockIdx.x & 31, ks = blockIdx.x >> 5;
  int lane = tid & 63, w = tid >> 6, wr = w & 1, wc = w >> 1;

  for (int idx = tid; idx < 64 * 8; idx += 256) {
    int row = idx >> 3, rr = idx & 7;
    frs_s[row][rr] = frs[(size_t)(bt * 64 + row) * NR_ + ks * 8 + rr];
  }
  for (int idx = tid; idx < 512; idx += 256) {      // coalesced 2KB
    int rr = idx >> 6, o = idx & 63;
    Wt_s[rr][o] = Wtail[(ks * 8 + rr) * 64 + o];
  }
  if (tid < 64) {
    rstd_s[tid] = rstd[bt * 64 + tid];
    if (ks == 0) {
      G_s[tid]   = G[tid];
      Bb_s[tid]  = Bb[tid];
      mur_s[tid] = mur[bt * 64 + tid];
    }
  }

  // X fragments in registers, reused across all 8 rules
  s16x8 xf[2][8];
  int browbase = bt * 64 + wr * 32;
#pragma unroll
  for (int rf = 0; rf < 2; rf++) {
    const unsigned short* xp = Xbf + (size_t)(browbase + rf * 16 + (lane & 15)) * 256 + (lane >> 4) * 8;
#pragma unroll
    for (int kc = 0; kc < 8; kc++)
      xf[rf][kc] = *(const s16x8*)(xp + kc * 32);
  }

  // stage rule 0 into buf 0 (32KB: 8 x 16B per thread, linear)
  const char* bbase = (const char*)Bpack + (size_t)ks * 8 * 32768;
  char* lbase = (char*)&Blds[0][0];
  {
#pragma unroll
    for (int p = 0; p < 8; p++)
      gload_lds16(bbase + tid * 16 + p * 4096, lbase + (tid >> 6) * 1024 + p * 4096);
  }
  __syncthreads();   // drains vmcnt(0): buf0 + LDS tables ready

  f32x4 S00 = {0.f,0.f,0.f,0.f}, S01 = S00, S10 = S00, S11 = S00;

  for (int rr = 0; rr < 8; rr++) {
    if (rr < 7) {    // issue next-rule stage before compute
      const char* src = bbase + (size_t)(rr + 1) * 32768;
      char* ldst = lbase + ((rr + 1) & 1) * 32768;
#pragma unroll
      for (int p = 0; p < 8; p++)
        gload_lds16(src + tid * 16 + p * 4096, ldst + (tid >> 6) * 1024 + p * 4096);
    }
    const unsigned short* bb = &Blds[rr & 1][0];
    f32x4 P00 = {0.f,0.f,0.f,0.f}, P01 = P00, P10 = P00, P11 = P00;
#pragma unroll
    for (int kc = 0; kc < 8; kc++) {
      s16x8 bf0 = *(const s16x8*)(bb + (size_t)((kc * 4 + wc * 2 + 0) * 64 + lane) * 8);
      s16x8 bf1 = *(const s16x8*)(bb + (size_t)((kc * 4 + wc * 2 + 1) * 64 + lane) * 8);
      P00 = __builtin_amdgcn_mfma_f32_16x16x32_bf16(xf[0][kc], bf0, P00, 0, 0, 0);
      P10 = __builtin_amdgcn_mfma_f32_16x16x32_bf16(xf[1][kc], bf0, P10, 0, 0, 0);
      P01 = __builtin_amdgcn_mfma_f32_16x16x32_bf16(xf[0][kc], bf1, P01, 0, 0, 0);
      P11 = __builtin_amdgcn_mfma_f32_16x16x32_bf16(xf[1][kc], bf1, P11, 0, 0, 0);
    }
#pragma unroll
    for (int q = 0; q < 4; q++) {
      float fv0 = frs_s[wr * 32 + 0  + (lane >> 4) * 4 + q][rr];
      float fv1 = frs_s[wr * 32 + 16 + (lane >> 4) * 4 + q][rr];
      S00[q] += fv0 * P00[q];  S01[q] += fv0 * P01[q];
      S10[q] += fv1 * P10[q];  S11[q] += fv1 * P11[q];
    }
    __syncthreads();   // next buffer staged
  }

  // tail GEMV + rstd scale (+ affine constant on ks==0) + atomic accumulate
  int o0 = wc * 32 + (lane & 15);
#pragma unroll
  for (int q = 0; q < 4; q++) {
    int lr0 = wr * 32 + 0  + (lane >> 4) * 4 + q;
    int lr1 = lr0 + 16;
    float t00 = 0.f, t01 = 0.f, t10 = 0.f, t11 = 0.f;
#pragma unroll
    for (int rr = 0; rr < 8; rr++) {
      float f0 = frs_s[lr0][rr], f1 = frs_s[lr1][rr];
      t00 = fmaf(f0, Wt_s[rr][o0],      t00);
      t01 = fmaf(f0, Wt_s[rr][o0 + 16], t01);
      t10 = fmaf(f1, Wt_s[rr][o0],      t10);
      t11 = fmaf(f1, Wt_s[rr][o0 + 16], t11);
    }
    float r0 = rstd_s[lr0], r1 = rstd_s[lr1];
    float c00 = 0.f, c01 = 0.f, c10 = 0.f, c11 = 0.f;
    if (ks == 0) {
      c00 = Bb_s[o0]      - mur_s[lr0] * G_s[o0];
      c01 = Bb_s[o0 + 16] - mur_s[lr0] * G_s[o0 + 16];
      c10 = Bb_s[o0]      - mur_s[lr1] * G_s[o0];
      c11 = Bb_s[o0 + 16] - mur_s[lr1] * G_s[o0 + 16];
    }
    size_t base0 = (size_t)(bt * 64 + lr0) * OUT_;
    size_t base1 = (size_t)(bt * 64 + lr1) * OUT_;
    atomicAdd(&out[base0 + o0],      r0 * (S00[q] + t00) + c00);
    atomicAdd(&out[base0 + o0 + 16], r0 * (S01[q] + t01) + c01);
    atomicAdd(&out[base1 + o0],      r1 * (S10[q] + t10) + c10);
    atomicAdd(&out[base1 + o0 + 16], r1 * (S11[q] + t11) + c11);
  }
}

extern "C" void kernel_launch(void* const* d_in, const int* in_sizes, int n_in,
                              void* d_out, int out_size, void* d_ws, size_t ws_size,
                              hipStream_t stream) {
  const float* X       = (const float*)d_in[0];
  const float* centers = (const float*)d_in[1];
  const float* sigmas  = (const float*)d_in[2];
  const float* gamma   = (const float*)d_in[3];
  const float* beta    = (const float*)d_in[4];
  const float* W       = (const float*)d_in[5];
  const float* bias    = (const float*)d_in[6];
  float* out = (float*)d_out;

  char* ws = (char*)d_ws;
  float* G             = (float*)(ws);                     // 256 B
  float* Bb            = (float*)(ws + 256);               // 256 B
  float* rstd          = (float*)(ws + 512);               // 8 KB
  float* mur           = (float*)(ws + 8704);              // 8 KB
  float* frs           = (float*)(ws + 16896);             // 1 MB
  unsigned short* Xbf  = (unsigned short*)(ws + 1065472);  // 1 MB
  unsigned short* Bpack= (unsigned short*)(ws + 2114048);  // 4 MB
  float* Gpart         = (float*)(ws + 6308352);           // 256 KB
  float* Bpart         = (float*)(ws + 6570496);           // 256 KB
  float* Wtail         = (float*)(ws + 6832640);           // 32 KB (total ~6.9 MB)

  hipLaunchKernelGGL(prep_frs_kernel, dim3(544), dim3(512), 0, stream,
                     X, centers, sigmas, W, gamma, beta,
                     Bpack, Gpart, Bpart, Wtail, frs, rstd, mur, Xbf, out);
  hipLaunchKernelGGL(reduce_kernel, dim3(OUT_), dim3(256), 0, stream,
                     W, gamma, beta, bias, Gpart, Bpart, G, Bb);
  hipLaunchKernelGGL(gemm_kernel, dim3(512), dim3(256), 0, stream,
                     Xbf, Bpack, frs, rstd, Wtail, G, Bb, mur, out);
}